// Round 1
// 3541.125 us; speedup vs baseline: 1.1222x; 1.1222x over previous
//
#include <hip/hip_runtime.h>
#include <cstdint>
#include <cstddef>

// Problem constants
#define Lc 6
#define Bc 4
#define Nc 1024
#define Dc 1024
#define Hn 16
#define HDc 64
#define Fc 4096

static constexpr long BND = (long)Bc * Nc * Dc;       // 4,194,304
static constexpr long DD  = (long)Dc * Dc;            // 1,048,576
#define FDl  ((long)Fc * Dc)                          // 4,194,304
static constexpr long BNF = (long)Bc * Nc * Fc;       // 16,777,216

typedef __attribute__((ext_vector_type(8))) short bf8_t;
typedef __attribute__((ext_vector_type(4))) float f4_t;

__device__ __forceinline__ float b2f(unsigned short u) {
  union { unsigned int i; float f; } v; v.i = ((unsigned int)u) << 16; return v.f;
}
__device__ __forceinline__ unsigned short f2b(float f) {
  union { float f; unsigned int i; } v; v.f = f;
  return (unsigned short)((v.i + 0x7fffu + ((v.i >> 16) & 1u)) >> 16);
}

__device__ __forceinline__ void gl_lds16(const unsigned short* g, unsigned short* l) {
  __builtin_amdgcn_global_load_lds(
      (const __attribute__((address_space(1))) void*)g,
      (__attribute__((address_space(3))) void*)l, 16, 0, 0);
}

// ---------------- fp32 -> bf16 cast ----------------
__global__ __launch_bounds__(256) void k_cast(const float* __restrict__ x,
                                              unsigned short* __restrict__ y, long n4) {
  long i = (long)blockIdx.x * 256 + threadIdx.x;
  if (i >= n4) return;
  float4 v = ((const float4*)x)[i];
  ushort4 o = { f2b(v.x), f2b(v.y), f2b(v.z), f2b(v.w) };
  ((ushort4*)y)[i] = o;
}

// ---------------- per-layer weight-pair concat cast: dst[l] = [cast(s1[l]); cast(s2[l])] ----
__global__ __launch_bounds__(256) void k_cast2(const float* __restrict__ s1,
                                               const float* __restrict__ s2,
                                               unsigned short* __restrict__ dst) {
  long i4 = (long)blockIdx.x * 256 + threadIdx.x;   // float4 index over Lc*2*DD/4
  long flat = i4 * 4;
  int l = (int)(flat / (2 * DD));
  long r = flat - (long)l * 2 * DD;
  const float* src = (r < DD) ? (s1 + (long)l * DD + r) : (s2 + (long)l * DD + (r - DD));
  float4 v = *(const float4*)src;
  ushort4 o = { f2b(v.x), f2b(v.y), f2b(v.z), f2b(v.w) };
  *(ushort4*)(dst + flat) = o;
}

// ---------------- per-layer bias-pair concat (fp32): dst[l] = [b1[l]; b2[l]] ----------------
__global__ __launch_bounds__(256) void k_bcat2(const float* __restrict__ b1,
                                               const float* __restrict__ b2,
                                               float* __restrict__ dst) {
  int i = blockIdx.x * 256 + threadIdx.x;  // over Lc*2048
  int l = i >> 11, r = i & 2047;
  dst[i] = (r < 1024) ? b1[l * 1024 + r] : b2[l * 1024 + (r - 1024)];
}

// ---------------- V-section of KV [rows=(b,n), ld=2048, V at col 1024+h*64+d] -> Vt[bh][d][n]
__global__ __launch_bounds__(256) void k_packvt2(const unsigned short* __restrict__ KV,
                                                 unsigned short* __restrict__ Vt) {
  __shared__ unsigned short T[64][72];
  const int bh = blockIdx.y, b = bh >> 4, h = bh & 15;
  const int n0 = blockIdx.x * 64;
  const int r = threadIdx.x >> 4;          // 0..15
  const int c4 = (threadIdx.x & 15) * 4;   // 0..60
  const unsigned short* src = KV + ((long)b * Nc + n0) * 2048 + 1024 + h * 64;
  #pragma unroll
  for (int it = 0; it < 4; ++it) {
    ushort4 v = *(const ushort4*)&src[(long)(it * 16 + r) * 2048 + c4];
    *(ushort4*)&T[it * 16 + r][c4] = v;
  }
  __syncthreads();
  unsigned short* dst = Vt + (long)bh * HDc * Nc + n0;
  #pragma unroll
  for (int it = 0; it < 4; ++it) {
    const int d = it * 16 + r;
    ushort4 v = { T[c4 + 0][d], T[c4 + 1][d], T[c4 + 2][d], T[c4 + 3][d] };
    *(ushort4*)&dst[(long)d * Nc + c4] = v;
  }
}

// ---------------- LayerNorm rows of X(+X2) [B*N, D]; dual fp32+bf16 out ----------------
__global__ __launch_bounds__(256) void k_ln(const float* __restrict__ X,
                                            const float* __restrict__ X2,
                                            const float* __restrict__ g,
                                            const float* __restrict__ be,
                                            float* __restrict__ Yf,
                                            unsigned short* __restrict__ Yb) {
  const long row = blockIdx.x;
  const float4* x4 = (const float4*)(X + row * Dc);
  const int tid = threadIdx.x, lane = tid & 63, wave = tid >> 6;
  float4 x = x4[tid];
  if (X2) {
    float4 x2 = ((const float4*)(X2 + row * Dc))[tid];
    x.x += x2.x; x.y += x2.y; x.z += x2.z; x.w += x2.w;
  }
  float s = x.x + x.y + x.z + x.w;
  float q = x.x * x.x + x.y * x.y + x.z * x.z + x.w * x.w;
  #pragma unroll
  for (int o = 32; o > 0; o >>= 1) { s += __shfl_down(s, o); q += __shfl_down(q, o); }
  __shared__ float rs[4], rq[4];
  if (lane == 0) { rs[wave] = s; rq[wave] = q; }
  __syncthreads();
  s = rs[0] + rs[1] + rs[2] + rs[3];
  q = rq[0] + rq[1] + rq[2] + rq[3];
  const float mean = s * (1.f / Dc);
  const float var = q * (1.f / Dc) - mean * mean;
  const float rstd = rsqrtf(var + 1e-5f);
  float4 gv = ((const float4*)g)[tid];
  float4 bv = ((const float4*)be)[tid];
  float4 y;
  y.x = (x.x - mean) * rstd * gv.x + bv.x;
  y.y = (x.y - mean) * rstd * gv.y + bv.y;
  y.z = (x.z - mean) * rstd * gv.z + bv.z;
  y.w = (x.w - mean) * rstd * gv.w + bv.w;
  if (Yf) ((float4*)(Yf + row * Dc))[tid] = y;
  if (Yb) {
    ushort4 o = { f2b(y.x), f2b(y.y), f2b(y.z), f2b(y.w) };
    ((ushort4*)(Yb + row * Dc))[tid] = o;
  }
}

// ---------------- Fused flash attention ----------------
#define QT 64
#define KT 128
#define PRS 132
__global__ __launch_bounds__(256, 2) void k_flash(
    const unsigned short* __restrict__ Q,   // [B,N,D] bf16 (pre-scaled), ld=Dc
    const unsigned short* __restrict__ Kg,  // [B,N,*] bf16, row stride ldk
    const unsigned short* __restrict__ Vt,  // [B*H, HD, N] bf16
    const float* __restrict__ mask,         // [N,N] fp32
    unsigned short* __restrict__ O, int ldk) {
  __shared__ __align__(16) unsigned short Qs[QT * 64];
  __shared__ __align__(16) unsigned short Ks[KT * 64];
  __shared__ __align__(16) unsigned short Vs[64 * KT];
  __shared__ __align__(16) unsigned short Ps[QT * PRS];

  const int tid = threadIdx.x;
  const int wave = tid >> 6, lane = tid & 63;
  const int lm = lane & 15, quad = lane >> 4;
  const int bh = blockIdx.y;
  const int b = bh >> 4, h = bh & 15;
  const int q0 = blockIdx.x * QT;

  const unsigned short* Qb = Q + ((long)b * Nc + q0) * Dc + h * HDc;
  const unsigned short* Kb = Kg + (long)b * Nc * ldk + h * HDc;
  const unsigned short* Vb = Vt + (long)bh * HDc * Nc;

  const int sr = tid >> 3, sc = (tid & 7) * 8;
  #pragma unroll
  for (int it = 0; it < QT / 32; ++it)
    gl_lds16(Qb + (long)(it * 32 + sr) * Dc + sc, &Qs[(it * 32 + sr) * 64 + sc]);

  f4_t Oa[4];
  #pragma unroll
  for (int jh = 0; jh < 4; ++jh) Oa[jh] = {0.f, 0.f, 0.f, 0.f};
  float m_run[4], l_run[4];
  #pragma unroll
  for (int r = 0; r < 4; ++r) { m_run[r] = -1e30f; l_run[r] = 0.f; }

  const int row_q = wave * 16 + quad * 4;
  const int vr = tid >> 4, vc = (tid & 15) * 8;

  for (int t = 0; t < Nc / KT; ++t) {
    #pragma unroll
    for (int it = 0; it < KT / 32; ++it)
      gl_lds16(Kb + (long)(t * KT + it * 32 + sr) * ldk + sc, &Ks[(it * 32 + sr) * 64 + sc]);
    #pragma unroll
    for (int it = 0; it < 4; ++it)
      gl_lds16(Vb + (long)(it * 16 + vr) * Nc + t * KT + vc, &Vs[(it * 16 + vr) * KT + vc]);
    __syncthreads();

    f4_t Sa[8];
    #pragma unroll
    for (int j = 0; j < 8; ++j) Sa[j] = {0.f, 0.f, 0.f, 0.f};
    #pragma unroll
    for (int kk = 0; kk < 2; ++kk) {
      const int kq = kk * 32 + quad * 8;
      bf8_t aq = *(const bf8_t*)&Qs[(wave * 16 + lm) * 64 + kq];
      #pragma unroll
      for (int j = 0; j < 8; ++j) {
        bf8_t bk = *(const bf8_t*)&Ks[(j * 16 + lm) * 64 + kq];
        Sa[j] = __builtin_amdgcn_mfma_f32_16x16x32_bf16(aq, bk, Sa[j], 0, 0, 0);
      }
    }

    float p[8][4], alpha[4];
    #pragma unroll
    for (int r = 0; r < 4; ++r) {
      const float* mrow = mask + (long)(q0 + row_q + r) * Nc + t * KT + lm;
      float sv[8];
      float mt = -1e30f;
      #pragma unroll
      for (int j = 0; j < 8; ++j) { sv[j] = Sa[j][r] + mrow[j * 16]; mt = fmaxf(mt, sv[j]); }
      #pragma unroll
      for (int o = 1; o < 16; o <<= 1) mt = fmaxf(mt, __shfl_xor(mt, o));
      const float mn = fmaxf(m_run[r], mt);
      alpha[r] = __expf(m_run[r] - mn);
      m_run[r] = mn;
      float sp = 0.f;
      #pragma unroll
      for (int j = 0; j < 8; ++j) { float e = __expf(sv[j] - mn); p[j][r] = e; sp += e; }
      #pragma unroll
      for (int o = 1; o < 16; o <<= 1) sp += __shfl_xor(sp, o);
      l_run[r] = l_run[r] * alpha[r] + sp;
    }

    #pragma unroll
    for (int r = 0; r < 4; ++r)
      #pragma unroll
      for (int j = 0; j < 8; ++j)
        Ps[(row_q + r) * PRS + j * 16 + lm] = f2b(p[j][r]);
    __syncthreads();

    #pragma unroll
    for (int jh = 0; jh < 4; ++jh)
      #pragma unroll
      for (int r = 0; r < 4; ++r) Oa[jh][r] *= alpha[r];
    #pragma unroll
    for (int kk = 0; kk < 4; ++kk) {
      const int kp = kk * 32 + quad * 8;
      bf8_t ap = *(const bf8_t*)&Ps[(wave * 16 + lm) * PRS + kp];
      #pragma unroll
      for (int jh = 0; jh < 4; ++jh) {
        bf8_t bv = *(const bf8_t*)&Vs[(jh * 16 + lm) * KT + kp];
        Oa[jh] = __builtin_amdgcn_mfma_f32_16x16x32_bf16(ap, bv, Oa[jh], 0, 0, 0);
      }
    }
    __syncthreads();
  }

  #pragma unroll
  for (int r = 0; r < 4; ++r) {
    const float inv = 1.f / l_run[r];
    unsigned short* orow = O + ((long)b * Nc + q0 + row_q + r) * Dc + h * HDc;
    #pragma unroll
    for (int jh = 0; jh < 4; ++jh) orow[jh * 16 + lm] = f2b(Oa[jh][r] * inv);
  }
}

// ---------------- shared MFMA GEMM core (2-phase, BK=64) ----------------
template <int BM, int BN, int MW, int NW>
__device__ __forceinline__ void mfma_loop(
    const unsigned short* __restrict__ A, const unsigned short* __restrict__ W,
    int K, int lda, int ldb, int m0, int n0,
    unsigned short* As, unsigned short* Bs,
    f4_t (&acc)[BM / MW / 16][BN / NW / 16]) {
  constexpr int WM = BM / MW, WN = BN / NW;
  constexpr int FM = WM / 16, FN = WN / 16;
  const int tid = threadIdx.x;
  const int wave = tid >> 6, lane = tid & 63;
  const int wm = wave / NW, wn = wave % NW;
  const int sr = tid >> 3, sc = (tid & 7) * 8;
  const int lm = lane & 15, quad = lane >> 4;

  for (int k0 = 0; k0 < K; k0 += 64) {
    #pragma unroll
    for (int it = 0; it < BM / 32; ++it) {
      const int rr = it * 32 + sr;
      gl_lds16(A + (long)(m0 + rr) * lda + (k0 + sc), &As[rr * 64 + sc]);
    }
    #pragma unroll
    for (int it = 0; it < BN / 32; ++it) {
      const int rr = it * 32 + sr;
      gl_lds16(W + (long)(n0 + rr) * ldb + (k0 + sc), &Bs[rr * 64 + sc]);
    }
    __syncthreads();
    #pragma unroll
    for (int kk = 0; kk < 2; ++kk) {
      const int kq = kk * 32 + quad * 8;
      bf8_t af[FM], bfr[FN];
      #pragma unroll
      for (int i = 0; i < FM; ++i)
        af[i] = *(const bf8_t*)&As[(wm * WM + i * 16 + lm) * 64 + kq];
      #pragma unroll
      for (int j = 0; j < FN; ++j)
        bfr[j] = *(const bf8_t*)&Bs[(wn * WN + j * 16 + lm) * 64 + kq];
      #pragma unroll
      for (int i = 0; i < FM; ++i)
        #pragma unroll
        for (int j = 0; j < FN; ++j)
          acc[i][j] = __builtin_amdgcn_mfma_f32_16x16x32_bf16(af[i], bfr[j], acc[i][j], 0, 0, 0);
    }
    __syncthreads();
  }
}

// ---------------- GEMM: C = A[M,K] * W[Nout,K]^T (+bias)*scale (+relu) (+res) ----------------
template <int BM, int BN, int MW, int NW>
__global__ __launch_bounds__(256, 2) void gemm_bt(
    const unsigned short* __restrict__ A, const unsigned short* __restrict__ W,
    const float* __restrict__ bias, const float* __restrict__ res,
    float* __restrict__ Cf, unsigned short* __restrict__ Cb,
    int K, int lda, int ldb, int ldc, float scale, int relu) {
  constexpr int WM = BM / MW, WN = BN / NW;
  constexpr int FM = WM / 16, FN = WN / 16;

  __shared__ __align__(16) unsigned short As[BM * 64];
  __shared__ __align__(16) unsigned short Bs[BN * 64];

  const int tid = threadIdx.x;
  const int wave = tid >> 6, lane = tid & 63;
  const int wm = wave / NW, wn = wave % NW;
  const int n0 = blockIdx.x * BN, m0 = blockIdx.y * BM;
  const int lm = lane & 15, quad = lane >> 4;

  f4_t acc[FM][FN];
  const f4_t zero = {0.f, 0.f, 0.f, 0.f};
  #pragma unroll
  for (int i = 0; i < FM; ++i)
    #pragma unroll
    for (int j = 0; j < FN; ++j) acc[i][j] = zero;

  mfma_loop<BM, BN, MW, NW>(A, W, K, lda, ldb, m0, n0, As, Bs, acc);

  #pragma unroll
  for (int i = 0; i < FM; ++i) {
    const int grow_base = m0 + wm * WM + i * 16 + quad * 4;
    #pragma unroll
    for (int j = 0; j < FN; ++j) {
      const int gcol = n0 + wn * WN + j * 16 + lm;
      const float bi = bias ? bias[gcol] : 0.f;
      #pragma unroll
      for (int r = 0; r < 4; ++r) {
        float v = (acc[i][j][r] + bi) * scale;
        if (relu) v = fmaxf(v, 0.f);
        const long cidx = (long)(grow_base + r) * ldc + gcol;
        if (res) v += res[cidx];
        if (Cf) Cf[cidx] = v;
        if (Cb) Cb[cidx] = f2b(v);
      }
    }
  }
}

// ---------------- Fused layer-start GEMM: Q1 | KV1 | KV2 in one saturated launch ----------
// All: M=4096, K=1024, lda=ldb=1024. grid.x = 40 (8 Q-blocks + 16 KV1 + 16 KV2), grid.y = 32.
__global__ __launch_bounds__(256, 2) void gemm_qkv(
    const unsigned short* __restrict__ Aq,  const unsigned short* __restrict__ Wq,
    const float* __restrict__ bq,
    const unsigned short* __restrict__ Ak1, const unsigned short* __restrict__ Wkv1,
    const float* __restrict__ bkv1,
    const unsigned short* __restrict__ Ak2, const unsigned short* __restrict__ Wkv2,
    const float* __restrict__ bkv2,
    unsigned short* __restrict__ Cq, unsigned short* __restrict__ Ckv1,
    unsigned short* __restrict__ Ckv2) {
  __shared__ __align__(16) unsigned short As[128 * 64];
  __shared__ __align__(16) unsigned short Bs[128 * 64];

  const int bx = blockIdx.x;
  const unsigned short *A, *W;
  const float* bias;
  unsigned short* C;
  int ldc, n0;
  float scale;
  if (bx < 8)       { A = Aq;  W = Wq;   bias = bq;   C = Cq;   ldc = 1024; n0 = bx * 128;        scale = 0.125f; }
  else if (bx < 24) { A = Ak1; W = Wkv1; bias = bkv1; C = Ckv1; ldc = 2048; n0 = (bx - 8) * 128;  scale = 1.f; }
  else              { A = Ak2; W = Wkv2; bias = bkv2; C = Ckv2; ldc = 2048; n0 = (bx - 24) * 128; scale = 1.f; }
  const int m0 = blockIdx.y * 128;

  const int tid = threadIdx.x;
  const int wave = tid >> 6, lane = tid & 63;
  const int wm = wave / 2, wn = wave % 2;
  const int lm = lane & 15, quad = lane >> 4;

  f4_t acc[4][4];
  const f4_t zero = {0.f, 0.f, 0.f, 0.f};
  #pragma unroll
  for (int i = 0; i < 4; ++i)
    #pragma unroll
    for (int j = 0; j < 4; ++j) acc[i][j] = zero;

  mfma_loop<128, 128, 2, 2>(A, W, 1024, 1024, 1024, m0, n0, As, Bs, acc);

  #pragma unroll
  for (int i = 0; i < 4; ++i) {
    const int grow_base = m0 + wm * 64 + i * 16 + quad * 4;
    #pragma unroll
    for (int j = 0; j < 4; ++j) {
      const int gcol = n0 + wn * 64 + j * 16 + lm;
      const float bi = bias[gcol];
      #pragma unroll
      for (int r = 0; r < 4; ++r) {
        float v = (acc[i][j][r] + bi) * scale;
        C[(long)(grow_base + r) * ldc + gcol] = f2b(v);
      }
    }
  }
}

// ---------------- FFN2 with split-K=2 (one launch, grid.z selects K-half) --------------
// A=hb [4096,4096], W=wf2[l] [1024,4096]. z=0: K rows 0..2047, +bias+res -> P0;
// z=1: K rows 2048..4095 -> P1. Reduction (P0+P1) fused into the following LayerNorm.
__global__ __launch_bounds__(256, 2) void gemm_f2s(
    const unsigned short* __restrict__ A, const unsigned short* __restrict__ W,
    const float* __restrict__ bias, const float* __restrict__ res,
    float* __restrict__ P0, float* __restrict__ P1) {
  __shared__ __align__(16) unsigned short As[128 * 64];
  __shared__ __align__(16) unsigned short Bs[128 * 64];

  const int z = blockIdx.z;
  const int kbeg = z * 2048;
  const int n0 = blockIdx.x * 128, m0 = blockIdx.y * 128;

  const int tid = threadIdx.x;
  const int wave = tid >> 6, lane = tid & 63;
  const int wm = wave / 2, wn = wave % 2;
  const int lm = lane & 15, quad = lane >> 4;

  f4_t acc[4][4];
  const f4_t zero = {0.f, 0.f, 0.f, 0.f};
  #pragma unroll
  for (int i = 0; i < 4; ++i)
    #pragma unroll
    for (int j = 0; j < 4; ++j) acc[i][j] = zero;

  mfma_loop<128, 128, 2, 2>(A + kbeg, W + kbeg, 2048, 4096, 4096, m0, n0, As, Bs, acc);

  float* P = z ? P1 : P0;
  #pragma unroll
  for (int i = 0; i < 4; ++i) {
    const int grow_base = m0 + wm * 64 + i * 16 + quad * 4;
    #pragma unroll
    for (int j = 0; j < 4; ++j) {
      const int gcol = n0 + wn * 64 + j * 16 + lm;
      const float bi = bias[gcol];
      #pragma unroll
      for (int r = 0; r < 4; ++r) {
        const long cidx = (long)(grow_base + r) * Dc + gcol;
        float v = acc[i][j][r];
        if (z == 0) v += bi + res[cidx];
        P[cidx] = v;
      }
    }
  }
}

extern "C" void kernel_launch(void* const* d_in, const int* in_sizes, int n_in,
                              void* d_out, int out_size, void* d_ws, size_t ws_size,
                              hipStream_t stream) {
  const float* feats    = (const float*)d_in[0];
  const float* enc      = (const float*)d_in[1];
  const float* trg_mask = (const float*)d_in[2];
  const float* src_mask = (const float*)d_in[3];
  const float* wq1 = (const float*)d_in[4];  const float* bq1 = (const float*)d_in[5];
  const float* wk1 = (const float*)d_in[6];  const float* bk1 = (const float*)d_in[7];
  const float* wv1 = (const float*)d_in[8];  const float* bv1 = (const float*)d_in[9];
  const float* wo1 = (const float*)d_in[10]; const float* bo1 = (const float*)d_in[11];
  const float* wq2 = (const float*)d_in[12]; const float* bq2 = (const float*)d_in[13];
  const float* wk2 = (const float*)d_in[14]; const float* bk2 = (const float*)d_in[15];
  const float* wv2 = (const float*)d_in[16]; const float* bv2 = (const float*)d_in[17];
  const float* wo2 = (const float*)d_in[18]; const float* bo2 = (const float*)d_in[19];
  const float* wf1 = (const float*)d_in[20]; const float* bf1 = (const float*)d_in[21];
  const float* wf2 = (const float*)d_in[22]; const float* bf2 = (const float*)d_in[23];
  const float* g1  = (const float*)d_in[24]; const float* be1 = (const float*)d_in[25];
  const float* g2  = (const float*)d_in[26]; const float* be2 = (const float*)d_in[27];
  const float* g3  = (const float*)d_in[28]; const float* be3 = (const float*)d_in[29];
  float* out = (float*)d_out;

  // ---- workspace carve ----
  char* wsp = (char*)d_ws;
  size_t off = 0;
  auto alloc = [&](size_t bytes) -> void* {
    void* p = wsp + off;
    off = (off + bytes + 255) & ~(size_t)255;
    return p;
  };
  unsigned short* wq1b  = (unsigned short*)alloc(Lc * DD * 2);
  unsigned short* wo1b  = (unsigned short*)alloc(Lc * DD * 2);
  unsigned short* wq2b  = (unsigned short*)alloc(Lc * DD * 2);
  unsigned short* wo2b  = (unsigned short*)alloc(Lc * DD * 2);
  unsigned short* wkv1b = (unsigned short*)alloc(Lc * 2 * DD * 2);  // [l][wk;wv]
  unsigned short* wkv2b = (unsigned short*)alloc(Lc * 2 * DD * 2);
  unsigned short* wf1b  = (unsigned short*)alloc(Lc * FDl * 2);
  unsigned short* wf2b  = (unsigned short*)alloc(Lc * FDl * 2);
  float* bkv1c = (float*)alloc(Lc * 2048 * 4);
  float* bkv2c = (float*)alloc(Lc * 2048 * 4);
  unsigned short* encb    = (unsigned short*)alloc(BND * 2);
  unsigned short* featall = (unsigned short*)alloc(Lc * BND * 2);   // all layers' feats bf16
  unsigned short* xb    = (unsigned short*)alloc(BND * 2);
  unsigned short* y1b   = (unsigned short*)alloc(BND * 2);
  unsigned short* y2b   = (unsigned short*)alloc(BND * 2);
  unsigned short* qb    = (unsigned short*)alloc(BND * 2);
  unsigned short* kvb   = (unsigned short*)alloc((long)Bc * Nc * 2048 * 2);  // attn1 KV
  unsigned short* kvb2  = (unsigned short*)alloc((long)Bc * Nc * 2048 * 2);  // attn2 KV
  unsigned short* vtb   = (unsigned short*)alloc(BND * 2);
  unsigned short* vtb2  = (unsigned short*)alloc(BND * 2);
  unsigned short* ob    = (unsigned short*)alloc(BND * 2);
  unsigned short* hb    = (unsigned short*)alloc(BNF * 2);
  float* y1f  = (float*)alloc(BND * 4);
  float* y2f  = (float*)alloc(BND * 4);
  float* pre  = (float*)alloc(BND * 4);
  float* pre2 = (float*)alloc(BND * 4);
  (void)ws_size; (void)in_sizes; (void)n_in; (void)out_size;

  auto cast = [&](const float* src, unsigned short* dst, long n) {
    long n4 = n / 4;
    k_cast<<<dim3((unsigned)((n4 + 255) / 256)), dim3(256), 0, stream>>>(src, dst, n4);
  };
  auto cast2 = [&](const float* s1, const float* s2, unsigned short* dst) {
    k_cast2<<<dim3((unsigned)(Lc * 2 * DD / 4 / 256)), dim3(256), 0, stream>>>(s1, s2, dst);
  };
  auto bcat2 = [&](const float* b1, const float* b2, float* dst) {
    k_bcat2<<<dim3(Lc * 2048 / 256), dim3(256), 0, stream>>>(b1, b2, dst);
  };
  auto gemm128 = [&](const unsigned short* A, const unsigned short* Wp, const float* bias,
                     const float* res, float* Cf, unsigned short* Cb,
                     int M, int Nout, int K, int lda, int ldb, int ldc, float scale, int relu) {
    gemm_bt<128, 128, 2, 2><<<dim3(Nout / 128, M / 128), dim3(256), 0, stream>>>(
        A, Wp, bias, res, Cf, Cb, K, lda, ldb, ldc, scale, relu);
  };
  auto gemm64 = [&](const unsigned short* A, const unsigned short* Wp, const float* bias,
                    const float* res, float* Cf, unsigned short* Cb,
                    int M, int Nout, int K, int lda, int ldb, int ldc, float scale, int relu) {
    gemm_bt<128, 64, 2, 2><<<dim3(Nout / 64, M / 128), dim3(256), 0, stream>>>(
        A, Wp, bias, res, Cf, Cb, K, lda, ldb, ldc, scale, relu);
  };
  auto flash = [&](const unsigned short* Kg, const unsigned short* Vt, const float* mask) {
    k_flash<<<dim3(Nc / QT, Bc * Hn), dim3(256), 0, stream>>>(qb, Kg, Vt, mask, ob, 2048);
  };
  auto ln = [&](const float* X, const float* X2, const float* gg, const float* bb,
                float* Yf, unsigned short* Yb) {
    k_ln<<<dim3(Bc * Nc), dim3(256), 0, stream>>>(X, X2, gg, bb, Yf, Yb);
  };
  auto packvt = [&](const unsigned short* kv, unsigned short* vt) {
    k_packvt2<<<dim3(Nc / 64, Bc * Hn), dim3(256), 0, stream>>>(kv, vt);
  };

  // ---- upfront casts / concats ----
  cast(wq1, wq1b, Lc * DD); cast(wo1, wo1b, Lc * DD);
  cast(wq2, wq2b, Lc * DD); cast(wo2, wo2b, Lc * DD);
  cast2(wk1, wv1, wkv1b);   cast2(wk2, wv2, wkv2b);
  bcat2(bk1, bv1, bkv1c);   bcat2(bk2, bv2, bkv2c);
  cast(wf1, wf1b, Lc * FDl); cast(wf2, wf2b, Lc * FDl);
  cast(enc, encb, BND);
  cast(feats, featall, (long)Lc * BND);

  for (int l = 0; l < Lc; ++l) {
    const float* featl = feats + (long)l * BND;
    const unsigned short* featb = featall + (long)l * BND;
    const unsigned short* kv2src = (l == 0) ? encb : xb;

    // ---- fused layer-start projections: Q1 (feat), KV1 (enc), KV2 (dec_out) ----
    gemm_qkv<<<dim3(40, 32), dim3(256), 0, stream>>>(
        featb, wq1b + (long)l * DD, bq1 + l * Dc,
        encb,  wkv1b + (long)l * 2 * DD, bkv1c + l * 2048,
        kv2src, wkv2b + (long)l * 2 * DD, bkv2c + l * 2048,
        qb, kvb, kvb2);
    packvt(kvb, vtb);
    packvt(kvb2, vtb2);

    // ---- attn1: softmax(QK^T)V with src_mask, then O-proj + residual + LN ----
    flash(kvb, vtb, src_mask);
    gemm64(ob, wo1b + (long)l * DD, bo1 + l * Dc, featl, pre, nullptr,
           Bc * Nc, Dc, Dc, Dc, Dc, Dc, 1.f, 0);
    ln(pre, nullptr, g1 + l * Dc, be1 + l * Dc, y1f, y1b);

    // ---- attn2: Q from y1, K/V precomputed from dec_out ----
    gemm64(y1b, wq2b + (long)l * DD, bq2 + l * Dc, nullptr, nullptr, qb,
           Bc * Nc, Dc, Dc, Dc, Dc, Dc, 0.125f, 0);
    flash(kvb2, vtb2, trg_mask);
    gemm64(ob, wo2b + (long)l * DD, bo2 + l * Dc, y1f, pre, nullptr,
           Bc * Nc, Dc, Dc, Dc, Dc, Dc, 1.f, 0);
    ln(pre, nullptr, g2 + l * Dc, be2 + l * Dc, y2f, y2b);

    // ---- FFN ----
    gemm128(y2b, wf1b + (long)l * FDl, bf1 + l * Fc, nullptr, nullptr, hb,
            Bc * Nc, Fc, Dc, Dc, Dc, Fc, 1.f, 1);
    gemm_f2s<<<dim3(8, 32, 2), dim3(256), 0, stream>>>(
        hb, wf2b + (long)l * FDl, bf2 + l * Dc, y2f, pre, pre2);
    ln(pre, pre2, g3 + l * Dc, be3 + l * Dc, out + (long)l * BND, xb);
  }
}

// Round 2
// 3162.716 us; speedup vs baseline: 1.2564x; 1.1196x over previous
//
#include <hip/hip_runtime.h>
#include <cstdint>
#include <cstddef>

// Problem constants
#define Lc 6
#define Bc 4
#define Nc 1024
#define Dc 1024
#define Hn 16
#define HDc 64
#define Fc 4096

static constexpr long BND = (long)Bc * Nc * Dc;       // 4,194,304
static constexpr long DD  = (long)Dc * Dc;            // 1,048,576
#define FDl  ((long)Fc * Dc)                          // 4,194,304
static constexpr long BNF = (long)Bc * Nc * Fc;       // 16,777,216
static constexpr long NN  = (long)Nc * Nc;            // 1,048,576

typedef __attribute__((ext_vector_type(8))) short bf8_t;
typedef __attribute__((ext_vector_type(4))) float f4_t;

__device__ __forceinline__ float b2f(unsigned short u) {
  union { unsigned int i; float f; } v; v.i = ((unsigned int)u) << 16; return v.f;
}
__device__ __forceinline__ unsigned short f2b(float f) {
  union { float f; unsigned int i; } v; v.f = f;
  return (unsigned short)((v.i + 0x7fffu + ((v.i >> 16) & 1u)) >> 16);
}

__device__ __forceinline__ void gl_lds16(const unsigned short* g, unsigned short* l) {
  __builtin_amdgcn_global_load_lds(
      (const __attribute__((address_space(1))) void*)g,
      (__attribute__((address_space(3))) void*)l, 16, 0, 0);
}

// ---------------- fp32 -> bf16 cast ----------------
__global__ __launch_bounds__(256) void k_cast(const float* __restrict__ x,
                                              unsigned short* __restrict__ y, long n4) {
  long i = (long)blockIdx.x * 256 + threadIdx.x;
  if (i >= n4) return;
  float4 v = ((const float4*)x)[i];
  ushort4 o = { f2b(v.x), f2b(v.y), f2b(v.z), f2b(v.w) };
  ((ushort4*)y)[i] = o;
}

// ---------------- per-layer weight-pair concat cast: dst[l] = [cast(s1[l]); cast(s2[l])] ----
__global__ __launch_bounds__(256) void k_cast2(const float* __restrict__ s1,
                                               const float* __restrict__ s2,
                                               unsigned short* __restrict__ dst) {
  long i4 = (long)blockIdx.x * 256 + threadIdx.x;   // float4 index over Lc*2*DD/4
  long flat = i4 * 4;
  int l = (int)(flat / (2 * DD));
  long r = flat - (long)l * 2 * DD;
  const float* src = (r < DD) ? (s1 + (long)l * DD + r) : (s2 + (long)l * DD + (r - DD));
  float4 v = *(const float4*)src;
  ushort4 o = { f2b(v.x), f2b(v.y), f2b(v.z), f2b(v.w) };
  *(ushort4*)(dst + flat) = o;
}

// ---------------- per-layer bias-pair concat (fp32): dst[l] = [b1[l]; b2[l]] ----------------
__global__ __launch_bounds__(256) void k_bcat2(const float* __restrict__ b1,
                                               const float* __restrict__ b2,
                                               float* __restrict__ dst) {
  int i = blockIdx.x * 256 + threadIdx.x;  // over Lc*2048
  int l = i >> 11, r = i & 2047;
  dst[i] = (r < 1024) ? b1[l * 1024 + r] : b2[l * 1024 + (r - 1024)];
}

// ---------------- V-section of KV [rows=(b,n), ld=2048, V at col 1024+h*64+d] -> Vt[bh][d][n]
// Dual-buffer variant: grid.y in [0,128); y>=64 handles the second KV/Vt pair.
__global__ __launch_bounds__(256) void k_packvt2(const unsigned short* __restrict__ KV1,
                                                 unsigned short* __restrict__ Vt1,
                                                 const unsigned short* __restrict__ KV2,
                                                 unsigned short* __restrict__ Vt2) {
  __shared__ unsigned short T[64][72];
  const int yy = blockIdx.y;
  const unsigned short* KV = (yy < 64) ? KV1 : KV2;
  unsigned short* Vt = (yy < 64) ? Vt1 : Vt2;
  const int bh = yy & 63, b = bh >> 4, h = bh & 15;
  const int n0 = blockIdx.x * 64;
  const int r = threadIdx.x >> 4;          // 0..15
  const int c4 = (threadIdx.x & 15) * 4;   // 0..60
  const unsigned short* src = KV + ((long)b * Nc + n0) * 2048 + 1024 + h * 64;
  #pragma unroll
  for (int it = 0; it < 4; ++it) {
    ushort4 v = *(const ushort4*)&src[(long)(it * 16 + r) * 2048 + c4];
    *(ushort4*)&T[it * 16 + r][c4] = v;
  }
  __syncthreads();
  unsigned short* dst = Vt + (long)bh * HDc * Nc + n0;
  #pragma unroll
  for (int it = 0; it < 4; ++it) {
    const int d = it * 16 + r;
    ushort4 v = { T[c4 + 0][d], T[c4 + 1][d], T[c4 + 2][d], T[c4 + 3][d] };
    *(ushort4*)&dst[(long)d * Nc + c4] = v;
  }
}

// ---------------- LayerNorm rows of X(+X2) [B*N, D]; dual fp32+bf16 out ----------------
__global__ __launch_bounds__(256) void k_ln(const float* __restrict__ X,
                                            const float* __restrict__ X2,
                                            const float* __restrict__ g,
                                            const float* __restrict__ be,
                                            float* __restrict__ Yf,
                                            unsigned short* __restrict__ Yb) {
  const long row = blockIdx.x;
  const float4* x4 = (const float4*)(X + row * Dc);
  const int tid = threadIdx.x, lane = tid & 63, wave = tid >> 6;
  float4 x = x4[tid];
  if (X2) {
    float4 x2 = ((const float4*)(X2 + row * Dc))[tid];
    x.x += x2.x; x.y += x2.y; x.z += x2.z; x.w += x2.w;
  }
  float s = x.x + x.y + x.z + x.w;
  float q = x.x * x.x + x.y * x.y + x.z * x.z + x.w * x.w;
  #pragma unroll
  for (int o = 32; o > 0; o >>= 1) { s += __shfl_down(s, o); q += __shfl_down(q, o); }
  __shared__ float rs[4], rq[4];
  if (lane == 0) { rs[wave] = s; rq[wave] = q; }
  __syncthreads();
  s = rs[0] + rs[1] + rs[2] + rs[3];
  q = rq[0] + rq[1] + rq[2] + rq[3];
  const float mean = s * (1.f / Dc);
  const float var = q * (1.f / Dc) - mean * mean;
  const float rstd = rsqrtf(var + 1e-5f);
  float4 gv = ((const float4*)g)[tid];
  float4 bv = ((const float4*)be)[tid];
  float4 y;
  y.x = (x.x - mean) * rstd * gv.x + bv.x;
  y.y = (x.y - mean) * rstd * gv.y + bv.y;
  y.z = (x.z - mean) * rstd * gv.z + bv.z;
  y.w = (x.w - mean) * rstd * gv.w + bv.w;
  if (Yf) ((float4*)(Yf + row * Dc))[tid] = y;
  if (Yb) {
    ushort4 o = { f2b(y.x), f2b(y.y), f2b(y.z), f2b(y.w) };
    ((ushort4*)(Yb + row * Dc))[tid] = o;
  }
}

// ---------------- Fused flash attention ----------------
// Grid 1024 blocks; XCD-contiguous remap so each XCD owns 8 bh-groups (K/V+mask L2-resident).
// Qs/Ks/Vs XOR-swizzled (chunk ^= (row&7)) to kill the 16-way ds_read_b128 bank conflict;
// global_load_lds writes linearly, so the swizzle is applied to the global SOURCE column
// and to the ds_read address (same involution on both sides).
#define QT 64
#define KT 128
#define PRS 132
__global__ __launch_bounds__(256, 2) void k_flash(
    const unsigned short* __restrict__ Q,   // [B,N,D] bf16 (pre-scaled), ld=Dc
    const unsigned short* __restrict__ Kg,  // [B,N,*] bf16, row stride ldk
    const unsigned short* __restrict__ Vt,  // [B*H, HD, N] bf16
    const unsigned short* __restrict__ mask,// [N,N] bf16
    unsigned short* __restrict__ O, int ldk) {
  __shared__ __align__(16) unsigned short Qs[QT * 64];
  __shared__ __align__(16) unsigned short Ks[KT * 64];
  __shared__ __align__(16) unsigned short Vs[64 * KT];
  __shared__ __align__(16) unsigned short Ps[QT * PRS];

  const int tid = threadIdx.x;
  const int wave = tid >> 6, lane = tid & 63;
  const int lm = lane & 15, quad = lane >> 4;

  // XCD-contiguous block remap (1024 blocks, 8 XCDs, bijective).
  const int wg = blockIdx.y * gridDim.x + blockIdx.x;
  const int wid = (wg & 7) * 128 + (wg >> 3);
  const int bh = wid >> 4;
  const int b = bh >> 4, h = bh & 15;
  const int q0 = (wid & 15) * QT;

  const unsigned short* Qb = Q + ((long)b * Nc + q0) * Dc + h * HDc;
  const unsigned short* Kb = Kg + (long)b * Nc * ldk + h * HDc;
  const unsigned short* Vb = Vt + (long)bh * HDc * Nc;

  const int sr = tid >> 3, sc = (tid & 7) * 8;
  const int scs = sc ^ ((sr & 7) << 3);          // swizzled source col (Q/K staging)
  #pragma unroll
  for (int it = 0; it < QT / 32; ++it)
    gl_lds16(Qb + (long)(it * 32 + sr) * Dc + scs, &Qs[(it * 32 + sr) * 64 + sc]);

  f4_t Oa[4];
  #pragma unroll
  for (int jh = 0; jh < 4; ++jh) Oa[jh] = {0.f, 0.f, 0.f, 0.f};
  float m_run[4], l_run[4];
  #pragma unroll
  for (int r = 0; r < 4; ++r) { m_run[r] = -1e30f; l_run[r] = 0.f; }

  const int row_q = wave * 16 + quad * 4;
  const int vr = tid >> 4, vc = (tid & 15) * 8;
  const int vcs = vc ^ ((vr & 7) << 3);          // swizzled source col (V staging)
  const int sw = (lm & 7) << 3;                  // read-side XOR (row&7 == lm&7 everywhere)

  for (int t = 0; t < Nc / KT; ++t) {
    #pragma unroll
    for (int it = 0; it < KT / 32; ++it)
      gl_lds16(Kb + (long)(t * KT + it * 32 + sr) * ldk + scs, &Ks[(it * 32 + sr) * 64 + sc]);
    #pragma unroll
    for (int it = 0; it < 4; ++it)
      gl_lds16(Vb + (long)(it * 16 + vr) * Nc + t * KT + (vcs), &Vs[(it * 16 + vr) * KT + vc]);
    __syncthreads();

    f4_t Sa[8];
    #pragma unroll
    for (int j = 0; j < 8; ++j) Sa[j] = {0.f, 0.f, 0.f, 0.f};
    __builtin_amdgcn_s_setprio(1);
    #pragma unroll
    for (int kk = 0; kk < 2; ++kk) {
      const int kq = kk * 32 + quad * 8;
      bf8_t aq = *(const bf8_t*)&Qs[(wave * 16 + lm) * 64 + (kq ^ sw)];
      #pragma unroll
      for (int j = 0; j < 8; ++j) {
        bf8_t bk = *(const bf8_t*)&Ks[(j * 16 + lm) * 64 + (kq ^ sw)];
        Sa[j] = __builtin_amdgcn_mfma_f32_16x16x32_bf16(aq, bk, Sa[j], 0, 0, 0);
      }
    }
    __builtin_amdgcn_s_setprio(0);

    float p[8][4], alpha[4];
    #pragma unroll
    for (int r = 0; r < 4; ++r) {
      const unsigned short* mrow = mask + (long)(q0 + row_q + r) * Nc + t * KT + lm;
      float sv[8];
      float mt = -1e30f;
      #pragma unroll
      for (int j = 0; j < 8; ++j) { sv[j] = Sa[j][r] + b2f(mrow[j * 16]); mt = fmaxf(mt, sv[j]); }
      #pragma unroll
      for (int o = 1; o < 16; o <<= 1) mt = fmaxf(mt, __shfl_xor(mt, o));
      const float mn = fmaxf(m_run[r], mt);
      alpha[r] = __expf(m_run[r] - mn);
      m_run[r] = mn;
      float sp = 0.f;
      #pragma unroll
      for (int j = 0; j < 8; ++j) { float e = __expf(sv[j] - mn); p[j][r] = e; sp += e; }
      #pragma unroll
      for (int o = 1; o < 16; o <<= 1) sp += __shfl_xor(sp, o);
      l_run[r] = l_run[r] * alpha[r] + sp;
    }

    #pragma unroll
    for (int r = 0; r < 4; ++r)
      #pragma unroll
      for (int j = 0; j < 8; ++j)
        Ps[(row_q + r) * PRS + j * 16 + lm] = f2b(p[j][r]);
    __syncthreads();

    #pragma unroll
    for (int jh = 0; jh < 4; ++jh)
      #pragma unroll
      for (int r = 0; r < 4; ++r) Oa[jh][r] *= alpha[r];
    __builtin_amdgcn_s_setprio(1);
    #pragma unroll
    for (int kk = 0; kk < 4; ++kk) {
      const int kp = kk * 32 + quad * 8;
      bf8_t ap = *(const bf8_t*)&Ps[(wave * 16 + lm) * PRS + kp];
      #pragma unroll
      for (int jh = 0; jh < 4; ++jh) {
        bf8_t bv = *(const bf8_t*)&Vs[(jh * 16 + lm) * KT + (kp ^ sw)];
        Oa[jh] = __builtin_amdgcn_mfma_f32_16x16x32_bf16(ap, bv, Oa[jh], 0, 0, 0);
      }
    }
    __builtin_amdgcn_s_setprio(0);
    __syncthreads();
  }

  #pragma unroll
  for (int r = 0; r < 4; ++r) {
    const float inv = 1.f / l_run[r];
    unsigned short* orow = O + ((long)b * Nc + q0 + row_q + r) * Dc + h * HDc;
    #pragma unroll
    for (int jh = 0; jh < 4; ++jh) orow[jh * 16 + lm] = f2b(Oa[jh][r] * inv);
  }
}

// ---------------- shared MFMA GEMM core (2-phase, BK=64) ----------------
template <int BM, int BN, int MW, int NW>
__device__ __forceinline__ void mfma_loop(
    const unsigned short* __restrict__ A, const unsigned short* __restrict__ W,
    int K, int lda, int ldb, int m0, int n0,
    unsigned short* As, unsigned short* Bs,
    f4_t (&acc)[BM / MW / 16][BN / NW / 16]) {
  constexpr int WM = BM / MW, WN = BN / NW;
  constexpr int FM = WM / 16, FN = WN / 16;
  const int tid = threadIdx.x;
  const int wave = tid >> 6, lane = tid & 63;
  const int wm = wave / NW, wn = wave % NW;
  const int sr = tid >> 3, sc = (tid & 7) * 8;
  const int lm = lane & 15, quad = lane >> 4;

  for (int k0 = 0; k0 < K; k0 += 64) {
    #pragma unroll
    for (int it = 0; it < BM / 32; ++it) {
      const int rr = it * 32 + sr;
      gl_lds16(A + (long)(m0 + rr) * lda + (k0 + sc), &As[rr * 64 + sc]);
    }
    #pragma unroll
    for (int it = 0; it < BN / 32; ++it) {
      const int rr = it * 32 + sr;
      gl_lds16(W + (long)(n0 + rr) * ldb + (k0 + sc), &Bs[rr * 64 + sc]);
    }
    __syncthreads();
    #pragma unroll
    for (int kk = 0; kk < 2; ++kk) {
      const int kq = kk * 32 + quad * 8;
      bf8_t af[FM], bfr[FN];
      #pragma unroll
      for (int i = 0; i < FM; ++i)
        af[i] = *(const bf8_t*)&As[(wm * WM + i * 16 + lm) * 64 + kq];
      #pragma unroll
      for (int j = 0; j < FN; ++j)
        bfr[j] = *(const bf8_t*)&Bs[(wn * WN + j * 16 + lm) * 64 + kq];
      #pragma unroll
      for (int i = 0; i < FM; ++i)
        #pragma unroll
        for (int j = 0; j < FN; ++j)
          acc[i][j] = __builtin_amdgcn_mfma_f32_16x16x32_bf16(af[i], bfr[j], acc[i][j], 0, 0, 0);
    }
    __syncthreads();
  }
}

// ---------------- GEMM: C = A[M,K] * W[Nout,K]^T (+bias)*scale (+relu) (+res) ----------------
template <int BM, int BN, int MW, int NW>
__global__ __launch_bounds__(256, 2) void gemm_bt(
    const unsigned short* __restrict__ A, const unsigned short* __restrict__ W,
    const float* __restrict__ bias, const float* __restrict__ res,
    float* __restrict__ Cf, unsigned short* __restrict__ Cb,
    int K, int lda, int ldb, int ldc, float scale, int relu) {
  constexpr int WM = BM / MW, WN = BN / NW;
  constexpr int FM = WM / 16, FN = WN / 16;

  __shared__ __align__(16) unsigned short As[BM * 64];
  __shared__ __align__(16) unsigned short Bs[BN * 64];

  const int tid = threadIdx.x;
  const int wave = tid >> 6, lane = tid & 63;
  const int wm = wave / NW, wn = wave % NW;
  const int n0 = blockIdx.x * BN, m0 = blockIdx.y * BM;
  const int lm = lane & 15, quad = lane >> 4;

  f4_t acc[FM][FN];
  const f4_t zero = {0.f, 0.f, 0.f, 0.f};
  #pragma unroll
  for (int i = 0; i < FM; ++i)
    #pragma unroll
    for (int j = 0; j < FN; ++j) acc[i][j] = zero;

  mfma_loop<BM, BN, MW, NW>(A, W, K, lda, ldb, m0, n0, As, Bs, acc);

  #pragma unroll
  for (int i = 0; i < FM; ++i) {
    const int grow_base = m0 + wm * WM + i * 16 + quad * 4;
    #pragma unroll
    for (int j = 0; j < FN; ++j) {
      const int gcol = n0 + wn * WN + j * 16 + lm;
      const float bi = bias ? bias[gcol] : 0.f;
      #pragma unroll
      for (int r = 0; r < 4; ++r) {
        float v = (acc[i][j][r] + bi) * scale;
        if (relu) v = fmaxf(v, 0.f);
        const long cidx = (long)(grow_base + r) * ldc + gcol;
        if (res) v += res[cidx];
        if (Cf) Cf[cidx] = v;
        if (Cb) Cb[cidx] = f2b(v);
      }
    }
  }
}

// ---------------- Fused layer-start GEMM: Q1 | KV1 | KV2 in one saturated launch ----------
// All: M=4096, K=1024, lda=ldb=1024. grid.x = 40 (8 Q-blocks + 16 KV1 + 16 KV2), grid.y = 32.
__global__ __launch_bounds__(256, 2) void gemm_qkv(
    const unsigned short* __restrict__ Aq,  const unsigned short* __restrict__ Wq,
    const float* __restrict__ bq,
    const unsigned short* __restrict__ Ak1, const unsigned short* __restrict__ Wkv1,
    const float* __restrict__ bkv1,
    const unsigned short* __restrict__ Ak2, const unsigned short* __restrict__ Wkv2,
    const float* __restrict__ bkv2,
    unsigned short* __restrict__ Cq, unsigned short* __restrict__ Ckv1,
    unsigned short* __restrict__ Ckv2) {
  __shared__ __align__(16) unsigned short As[128 * 64];
  __shared__ __align__(16) unsigned short Bs[128 * 64];

  const int bx = blockIdx.x;
  const unsigned short *A, *W;
  const float* bias;
  unsigned short* C;
  int ldc, n0;
  float scale;
  if (bx < 8)       { A = Aq;  W = Wq;   bias = bq;   C = Cq;   ldc = 1024; n0 = bx * 128;        scale = 0.125f; }
  else if (bx < 24) { A = Ak1; W = Wkv1; bias = bkv1; C = Ckv1; ldc = 2048; n0 = (bx - 8) * 128;  scale = 1.f; }
  else              { A = Ak2; W = Wkv2; bias = bkv2; C = Ckv2; ldc = 2048; n0 = (bx - 24) * 128; scale = 1.f; }
  const int m0 = blockIdx.y * 128;

  const int tid = threadIdx.x;
  const int wave = tid >> 6, lane = tid & 63;
  const int wm = wave / 2, wn = wave % 2;
  const int lm = lane & 15, quad = lane >> 4;

  f4_t acc[4][4];
  const f4_t zero = {0.f, 0.f, 0.f, 0.f};
  #pragma unroll
  for (int i = 0; i < 4; ++i)
    #pragma unroll
    for (int j = 0; j < 4; ++j) acc[i][j] = zero;

  mfma_loop<128, 128, 2, 2>(A, W, 1024, 1024, 1024, m0, n0, As, Bs, acc);

  #pragma unroll
  for (int i = 0; i < 4; ++i) {
    const int grow_base = m0 + wm * 64 + i * 16 + quad * 4;
    #pragma unroll
    for (int j = 0; j < 4; ++j) {
      const int gcol = n0 + wn * 64 + j * 16 + lm;
      const float bi = bias[gcol];
      #pragma unroll
      for (int r = 0; r < 4; ++r) {
        float v = (acc[i][j][r] + bi) * scale;
        C[(long)(grow_base + r) * ldc + gcol] = f2b(v);
      }
    }
  }
}

// ---------------- FFN2 with split-K=2 (one launch, grid.z selects K-half) --------------
__global__ __launch_bounds__(256, 2) void gemm_f2s(
    const unsigned short* __restrict__ A, const unsigned short* __restrict__ W,
    const float* __restrict__ bias, const float* __restrict__ res,
    float* __restrict__ P0, float* __restrict__ P1) {
  __shared__ __align__(16) unsigned short As[128 * 64];
  __shared__ __align__(16) unsigned short Bs[128 * 64];

  const int z = blockIdx.z;
  const int kbeg = z * 2048;
  const int n0 = blockIdx.x * 128, m0 = blockIdx.y * 128;

  const int tid = threadIdx.x;
  const int wave = tid >> 6, lane = tid & 63;
  const int wm = wave / 2, wn = wave % 2;
  const int lm = lane & 15, quad = lane >> 4;

  f4_t acc[4][4];
  const f4_t zero = {0.f, 0.f, 0.f, 0.f};
  #pragma unroll
  for (int i = 0; i < 4; ++i)
    #pragma unroll
    for (int j = 0; j < 4; ++j) acc[i][j] = zero;

  mfma_loop<128, 128, 2, 2>(A + kbeg, W + kbeg, 2048, 4096, 4096, m0, n0, As, Bs, acc);

  float* P = z ? P1 : P0;
  #pragma unroll
  for (int i = 0; i < 4; ++i) {
    const int grow_base = m0 + wm * 64 + i * 16 + quad * 4;
    #pragma unroll
    for (int j = 0; j < 4; ++j) {
      const int gcol = n0 + wn * 64 + j * 16 + lm;
      const float bi = bias[gcol];
      #pragma unroll
      for (int r = 0; r < 4; ++r) {
        const long cidx = (long)(grow_base + r) * Dc + gcol;
        float v = acc[i][j][r];
        if (z == 0) v += bi + res[cidx];
        P[cidx] = v;
      }
    }
  }
}

extern "C" void kernel_launch(void* const* d_in, const int* in_sizes, int n_in,
                              void* d_out, int out_size, void* d_ws, size_t ws_size,
                              hipStream_t stream) {
  const float* feats    = (const float*)d_in[0];
  const float* enc      = (const float*)d_in[1];
  const float* trg_mask = (const float*)d_in[2];
  const float* src_mask = (const float*)d_in[3];
  const float* wq1 = (const float*)d_in[4];  const float* bq1 = (const float*)d_in[5];
  const float* wk1 = (const float*)d_in[6];  const float* bk1 = (const float*)d_in[7];
  const float* wv1 = (const float*)d_in[8];  const float* bv1 = (const float*)d_in[9];
  const float* wo1 = (const float*)d_in[10]; const float* bo1 = (const float*)d_in[11];
  const float* wq2 = (const float*)d_in[12]; const float* bq2 = (const float*)d_in[13];
  const float* wk2 = (const float*)d_in[14]; const float* bk2 = (const float*)d_in[15];
  const float* wv2 = (const float*)d_in[16]; const float* bv2 = (const float*)d_in[17];
  const float* wo2 = (const float*)d_in[18]; const float* bo2 = (const float*)d_in[19];
  const float* wf1 = (const float*)d_in[20]; const float* bf1 = (const float*)d_in[21];
  const float* wf2 = (const float*)d_in[22]; const float* bf2 = (const float*)d_in[23];
  const float* g1  = (const float*)d_in[24]; const float* be1 = (const float*)d_in[25];
  const float* g2  = (const float*)d_in[26]; const float* be2 = (const float*)d_in[27];
  const float* g3  = (const float*)d_in[28]; const float* be3 = (const float*)d_in[29];
  float* out = (float*)d_out;

  // ---- workspace carve ----
  char* wsp = (char*)d_ws;
  size_t off = 0;
  auto alloc = [&](size_t bytes) -> void* {
    void* p = wsp + off;
    off = (off + bytes + 255) & ~(size_t)255;
    return p;
  };
  unsigned short* wq1b  = (unsigned short*)alloc(Lc * DD * 2);
  unsigned short* wo1b  = (unsigned short*)alloc(Lc * DD * 2);
  unsigned short* wq2b  = (unsigned short*)alloc(Lc * DD * 2);
  unsigned short* wo2b  = (unsigned short*)alloc(Lc * DD * 2);
  unsigned short* wkv1b = (unsigned short*)alloc(Lc * 2 * DD * 2);  // [l][wk;wv]
  unsigned short* wkv2b = (unsigned short*)alloc(Lc * 2 * DD * 2);
  unsigned short* wf1b  = (unsigned short*)alloc(Lc * FDl * 2);
  unsigned short* wf2b  = (unsigned short*)alloc(Lc * FDl * 2);
  float* bkv1c = (float*)alloc(Lc * 2048 * 4);
  float* bkv2c = (float*)alloc(Lc * 2048 * 4);
  unsigned short* encb    = (unsigned short*)alloc(BND * 2);
  unsigned short* featall = (unsigned short*)alloc(Lc * BND * 2);   // all layers' feats bf16
  unsigned short* smaskb  = (unsigned short*)alloc(NN * 2);
  unsigned short* tmaskb  = (unsigned short*)alloc(NN * 2);
  unsigned short* xb    = (unsigned short*)alloc(BND * 2);
  unsigned short* y1b   = (unsigned short*)alloc(BND * 2);
  unsigned short* y2b   = (unsigned short*)alloc(BND * 2);
  unsigned short* qb    = (unsigned short*)alloc(BND * 2);
  unsigned short* kvb   = (unsigned short*)alloc((long)Bc * Nc * 2048 * 2);  // attn1 KV
  unsigned short* kvb2  = (unsigned short*)alloc((long)Bc * Nc * 2048 * 2);  // attn2 KV
  unsigned short* vtb   = (unsigned short*)alloc(BND * 2);
  unsigned short* vtb2  = (unsigned short*)alloc(BND * 2);
  unsigned short* ob    = (unsigned short*)alloc(BND * 2);
  unsigned short* hb    = (unsigned short*)alloc(BNF * 2);
  float* y1f  = (float*)alloc(BND * 4);
  float* y2f  = (float*)alloc(BND * 4);
  float* pre  = (float*)alloc(BND * 4);
  float* pre2 = (float*)alloc(BND * 4);
  (void)ws_size; (void)in_sizes; (void)n_in; (void)out_size;

  auto cast = [&](const float* src, unsigned short* dst, long n) {
    long n4 = n / 4;
    k_cast<<<dim3((unsigned)((n4 + 255) / 256)), dim3(256), 0, stream>>>(src, dst, n4);
  };
  auto cast2 = [&](const float* s1, const float* s2, unsigned short* dst) {
    k_cast2<<<dim3((unsigned)(Lc * 2 * DD / 4 / 256)), dim3(256), 0, stream>>>(s1, s2, dst);
  };
  auto bcat2 = [&](const float* b1, const float* b2, float* dst) {
    k_bcat2<<<dim3(Lc * 2048 / 256), dim3(256), 0, stream>>>(b1, b2, dst);
  };
  auto gemm128 = [&](const unsigned short* A, const unsigned short* Wp, const float* bias,
                     const float* res, float* Cf, unsigned short* Cb,
                     int M, int Nout, int K, int lda, int ldb, int ldc, float scale, int relu) {
    gemm_bt<128, 128, 2, 2><<<dim3(Nout / 128, M / 128), dim3(256), 0, stream>>>(
        A, Wp, bias, res, Cf, Cb, K, lda, ldb, ldc, scale, relu);
  };
  auto gemm64 = [&](const unsigned short* A, const unsigned short* Wp, const float* bias,
                    const float* res, float* Cf, unsigned short* Cb,
                    int M, int Nout, int K, int lda, int ldb, int ldc, float scale, int relu) {
    gemm_bt<128, 64, 2, 2><<<dim3(Nout / 64, M / 128), dim3(256), 0, stream>>>(
        A, Wp, bias, res, Cf, Cb, K, lda, ldb, ldc, scale, relu);
  };
  auto flash = [&](const unsigned short* Kg, const unsigned short* Vt, const unsigned short* mask) {
    k_flash<<<dim3(Nc / QT, Bc * Hn), dim3(256), 0, stream>>>(qb, Kg, Vt, mask, ob, 2048);
  };
  auto ln = [&](const float* X, const float* X2, const float* gg, const float* bb,
                float* Yf, unsigned short* Yb) {
    k_ln<<<dim3(Bc * Nc), dim3(256), 0, stream>>>(X, X2, gg, bb, Yf, Yb);
  };
  auto packvt_dual = [&]() {
    k_packvt2<<<dim3(Nc / 64, 2 * Bc * Hn), dim3(256), 0, stream>>>(kvb, vtb, kvb2, vtb2);
  };

  // ---- upfront casts / concats ----
  cast(wq1, wq1b, Lc * DD); cast(wo1, wo1b, Lc * DD);
  cast(wq2, wq2b, Lc * DD); cast(wo2, wo2b, Lc * DD);
  cast2(wk1, wv1, wkv1b);   cast2(wk2, wv2, wkv2b);
  bcat2(bk1, bv1, bkv1c);   bcat2(bk2, bv2, bkv2c);
  cast(wf1, wf1b, Lc * FDl); cast(wf2, wf2b, Lc * FDl);
  cast(enc, encb, BND);
  cast(feats, featall, (long)Lc * BND);
  cast(src_mask, smaskb, NN);
  cast(trg_mask, tmaskb, NN);

  for (int l = 0; l < Lc; ++l) {
    const float* featl = feats + (long)l * BND;
    const unsigned short* featb = featall + (long)l * BND;
    const unsigned short* kv2src = (l == 0) ? encb : xb;

    // ---- fused layer-start projections: Q1 (feat), KV1 (enc), KV2 (dec_out) ----
    gemm_qkv<<<dim3(40, 32), dim3(256), 0, stream>>>(
        featb, wq1b + (long)l * DD, bq1 + l * Dc,
        encb,  wkv1b + (long)l * 2 * DD, bkv1c + l * 2048,
        kv2src, wkv2b + (long)l * 2 * DD, bkv2c + l * 2048,
        qb, kvb, kvb2);
    packvt_dual();

    // ---- attn1: softmax(QK^T)V with src_mask, then O-proj + residual + LN ----
    flash(kvb, vtb, smaskb);
    gemm64(ob, wo1b + (long)l * DD, bo1 + l * Dc, featl, pre, nullptr,
           Bc * Nc, Dc, Dc, Dc, Dc, Dc, 1.f, 0);
    ln(pre, nullptr, g1 + l * Dc, be1 + l * Dc, y1f, y1b);

    // ---- attn2: Q from y1, K/V precomputed from dec_out ----
    gemm64(y1b, wq2b + (long)l * DD, bq2 + l * Dc, nullptr, nullptr, qb,
           Bc * Nc, Dc, Dc, Dc, Dc, Dc, 0.125f, 0);
    flash(kvb2, vtb2, tmaskb);
    gemm64(ob, wo2b + (long)l * DD, bo2 + l * Dc, y1f, pre, nullptr,
           Bc * Nc, Dc, Dc, Dc, Dc, Dc, 1.f, 0);
    ln(pre, nullptr, g2 + l * Dc, be2 + l * Dc, y2f, y2b);

    // ---- FFN ----
    gemm128(y2b, wf1b + (long)l * FDl, bf1 + l * Fc, nullptr, nullptr, hb,
            Bc * Nc, Fc, Dc, Dc, Dc, Fc, 1.f, 1);
    gemm_f2s<<<dim3(8, 32, 2), dim3(256), 0, stream>>>(
        hb, wf2b + (long)l * FDl, bf2 + l * Dc, y2f, pre, pre2);
    ln(pre, pre2, g3 + l * Dc, be3 + l * Dc, out + (long)l * BND, xb);
  }
}